// Round 4
// baseline (7716.196 us; speedup 1.0000x reference)
//
#include <hip/hip_runtime.h>

// GraphFeatureTokenizer: B=8, HID=768, K=32, TOK=4, MAXLEN=15360
// Outputs concatenated flat (float32): feature [8,15360,768], mask [8,15360], index [8,15360,2]
//
// R3: fuse embedding gather into the lap-projection j-loop.
// Post-mortem R2: nt stores changed nothing (FETCH 591->591 MB) -> fetch is
// structural L2-miss traffic (random rows >> 4MB/XCD L2). Time breakdown:
// ~77us VALU (lap proj) + latency-bound gather tail, serialized per block.
// Fix: split j-loop into 4 chunks of 16; issue 4 tokens' embed-row loads
// (16 x float4 regs) before each chunk, consume after it. Each chunk is
// ~2048 cyc of VALU issue per wave -> covers ~700cyc LLC gather latency.
// Prediction: traffic flat, dispatch 296 -> ~210-240us.

constexpr int BGRAPH = 8;
constexpr int HID    = 768;
constexpr int MAXLEN = 15360;
constexpr int TB     = 16;    // tokens per block
constexpr int BLOCK  = 192;   // 192 threads * float4 = 768 cols

typedef float nfloat4 __attribute__((ext_vector_type(4)));

__device__ __forceinline__ void st_nt4(float4* p, float4 v) {
    nfloat4 nv;
    nv.x = v.x; nv.y = v.y; nv.z = v.z; nv.w = v.w;
    __builtin_nontemporal_store(nv, (nfloat4*)p);
}
__device__ __forceinline__ void st_nt1(float* p, float v) {
    __builtin_nontemporal_store(v, p);
}

__global__ __launch_bounds__(BLOCK)
void gft_kernel(const float* __restrict__ embedW,   // [50257,768]
                const float* __restrict__ lapW,     // [64,768]
                const float* __restrict__ orderW,   // [2,768]
                const float* __restrict__ eig,      // [N,32]
                const int*   __restrict__ node_data,// [N,4]
                const int*   __restrict__ edge_data,// [E,4]
                const int*   __restrict__ edge_index,// [2,E]
                const int*   __restrict__ node_num, // [8]
                const int*   __restrict__ edge_num, // [8]
                int E,
                float* __restrict__ outF,
                float* __restrict__ outM,
                float* __restrict__ outI)
{
    const int b   = blockIdx.y;
    const int t0  = blockIdx.x * TB;
    const int tid = threadIdx.x;

    // prefix sums over the 8 graphs (uniform scalar loads)
    int ns = 0, es = 0, nn = 0, en = 0;
    #pragma unroll
    for (int g = 0; g < BGRAPH; ++g) {
        int nv = node_num[g], ev = edge_num[g];
        if (g < b)  { ns += nv; es += ev; }
        if (g == b) { nn = nv;  en = ev; }
    }
    const int seq = nn + en;

    float* rowF = outF + ((size_t)b * MAXLEN + t0) * HID;
    const float4 z4 = make_float4(0.f, 0.f, 0.f, 0.f);

    if (t0 >= seq) {
        // whole tile is padding: zero feature, mask=1, index=0
        #pragma unroll
        for (int tok = 0; tok < TB; ++tok) {
            st_nt4((float4*)(rowF + (size_t)tok * HID) + tid, z4);
        }
        if (tid < TB) {
            int t = t0 + tid;
            st_nt1(&outM[b * MAXLEN + t], 1.0f);
            st_nt1(&outI[((size_t)b * MAXLEN + t) * 2 + 0], 0.f);
            st_nt1(&outI[((size_t)b * MAXLEN + t) * 2 + 1], 0.f);
        }
        return;
    }

    __shared__ float sh_eig[64][TB];   // [j][tok]
    __shared__ int   sh_ids[TB][4];
    __shared__ int   sh_i0[TB], sh_i1[TB], sh_gA[TB], sh_gB[TB];

    // ---- phase 0: token metadata (one thread per token) ----
    if (tid < TB) {
        int t = t0 + tid;
        int i0 = 0, i1 = 0, gA = -1, gB = -1;
        int id0 = 0, id1 = 0, id2 = 0, id3 = 0;
        if (t < seq) {
            if (t < nn) {               // node token
                int g = ns + t;
                i0 = t; i1 = t; gA = g; gB = g;
                id0 = node_data[g * 4 + 0];
                id1 = node_data[g * 4 + 1];
                id2 = node_data[g * 4 + 2];
                id3 = node_data[g * 4 + 3];
            } else {                    // edge token
                int ge = es + (t - nn);
                i0 = edge_index[ge];
                i1 = edge_index[E + ge];
                gA = ns + i0; gB = ns + i1;
                id0 = edge_data[ge * 4 + 0];
                id1 = edge_data[ge * 4 + 1];
                id2 = edge_data[ge * 4 + 2];
                id3 = edge_data[ge * 4 + 3];
            }
        }
        sh_i0[tid] = i0; sh_i1[tid] = i1;
        sh_gA[tid] = gA; sh_gB[tid] = gB;
        sh_ids[tid][0] = id0; sh_ids[tid][1] = id1;
        sh_ids[tid][2] = id2; sh_ids[tid][3] = id3;
    }
    __syncthreads();

    // ---- phase 1: stage eig pairs into LDS [j][tok] (first 128 threads, 8 j's each) ----
    if (tid < 128) {
        int tok   = tid >> 3;           // 0..15
        int jbase = (tid & 7) * 8;      // 0..56
        int gA = sh_gA[tok], gB = sh_gB[tok];
        #pragma unroll
        for (int jj = 0; jj < 8; ++jj) {
            int j = jbase + jj;
            float v = 0.f;
            if (j < 32) { if (gA >= 0) v = eig[(size_t)gA * 32 + j]; }
            else        { if (gB >= 0) v = eig[(size_t)gB * 32 + (j - 32)]; }
            sh_eig[j][tok] = v;
        }
    }
    __syncthreads();

    // mask/index writes — independent of the heavy phases, issue early
    if (tid < TB) {
        int t = t0 + tid;
        bool pad = (t >= seq);
        st_nt1(&outM[b * MAXLEN + t], pad ? 1.0f : 0.0f);
        st_nt1(&outI[((size_t)b * MAXLEN + t) * 2 + 0], pad ? 0.f : (float)sh_i0[tid]);
        st_nt1(&outI[((size_t)b * MAXLEN + t) * 2 + 1], pad ? 0.f : (float)sh_i1[tid]);
    }

    // ---- phase 2+3 fused: lap projection j-loop with embedding gathers
    //      interleaved in 4 groups of (4 tokens x 4 rows) ----
    float4 acc[TB];
    #pragma unroll
    for (int i = 0; i < TB; ++i) acc[i] = z4;

    #pragma unroll
    for (int grp = 0; grp < 4; ++grp) {
        // issue this group's 16 embedding-row loads (independent of j-loop)
        float4 e[4][4];
        #pragma unroll
        for (int tk = 0; tk < 4; ++tk) {
            const int tok = grp * 4 + tk;
            #pragma unroll
            for (int r = 0; r < 4; ++r) {
                e[tk][r] = ((const float4*)(embedW + (size_t)sh_ids[tok][r] * HID))[tid];
            }
        }
        // 16 j-iterations of the lap projection (covers gather latency)
        for (int j = grp * 16; j < grp * 16 + 16; ++j) {
            float4 w = ((const float4*)(lapW + j * HID))[tid];
            const float4* ev = (const float4*)(&sh_eig[j][0]);
            #pragma unroll
            for (int q = 0; q < TB / 4; ++q) {
                float4 e4 = ev[q];
                acc[q*4+0].x += e4.x * w.x; acc[q*4+0].y += e4.x * w.y;
                acc[q*4+0].z += e4.x * w.z; acc[q*4+0].w += e4.x * w.w;
                acc[q*4+1].x += e4.y * w.x; acc[q*4+1].y += e4.y * w.y;
                acc[q*4+1].z += e4.y * w.z; acc[q*4+1].w += e4.y * w.w;
                acc[q*4+2].x += e4.z * w.x; acc[q*4+2].y += e4.z * w.y;
                acc[q*4+2].z += e4.z * w.z; acc[q*4+2].w += e4.z * w.w;
                acc[q*4+3].x += e4.w * w.x; acc[q*4+3].y += e4.w * w.y;
                acc[q*4+3].z += e4.w * w.z; acc[q*4+3].w += e4.w * w.w;
            }
        }
        // consume: embedding sums commute with the lap accumulation
        #pragma unroll
        for (int tk = 0; tk < 4; ++tk) {
            const int tok = grp * 4 + tk;
            #pragma unroll
            for (int r = 0; r < 4; ++r) {
                acc[tok].x += e[tk][r].x; acc[tok].y += e[tk][r].y;
                acc[tok].z += e[tk][r].z; acc[tok].w += e[tk][r].w;
            }
        }
    }

    // ---- epilogue: order row + store ----
    #pragma unroll
    for (int tok = 0; tok < TB; ++tok) {
        int t = t0 + tok;
        float4* dst = (float4*)(rowF + (size_t)tok * HID) + tid;
        if (t >= seq) { st_nt4(dst, z4); continue; }
        float4 s = acc[tok];
        int ord = (sh_i0[tok] == sh_i1[tok]) ? 1 : 0;
        float4 o = ((const float4*)(orderW + (size_t)ord * HID))[tid];
        s.x += o.x; s.y += o.y; s.z += o.z; s.w += o.w;
        st_nt4(dst, s);
    }
}

extern "C" void kernel_launch(void* const* d_in, const int* in_sizes, int n_in,
                              void* d_out, int out_size, void* d_ws, size_t ws_size,
                              hipStream_t stream) {
    const float* embedW     = (const float*)d_in[0];
    const float* lapW       = (const float*)d_in[1];
    const float* orderW     = (const float*)d_in[2];
    const float* eig        = (const float*)d_in[3];
    const int*   node_data  = (const int*)d_in[4];
    const int*   edge_data  = (const int*)d_in[5];
    const int*   edge_index = (const int*)d_in[6];
    const int*   node_num   = (const int*)d_in[7];
    const int*   edge_num   = (const int*)d_in[8];
    const int E = in_sizes[6] / 2;

    float* outF = (float*)d_out;
    float* outM = outF + (size_t)BGRAPH * MAXLEN * HID;
    float* outI = outM + (size_t)BGRAPH * MAXLEN;

    dim3 grid(MAXLEN / TB, BGRAPH);
    gft_kernel<<<grid, BLOCK, 0, stream>>>(embedW, lapW, orderW, eig,
                                           node_data, edge_data, edge_index,
                                           node_num, edge_num, E,
                                           outF, outM, outI);
}

// Round 8
// 652.539 us; speedup vs baseline: 11.8249x; 11.8249x over previous
//
#include <hip/hip_runtime.h>

// GraphFeatureTokenizer: B=8, HID=768, K=32, TOK=4, MAXLEN=15360
// Outputs concatenated flat (float32): feature [8,15360,768], mask [8,15360], index [8,15360,2]
//
// R5: revert to R2 structure (296us dispatch, known good). Single change:
// phase 3 gathers batched 4 tokens deep (16 float4 loads in flight, then
// consume). Phase 2 untouched -> compiler's phase-2 register chunking
// preserved (R3 post-mortem: threading gather regs through the j-loop
// spilled acc to scratch, 17GB of traffic, 25x regression).
// HBM bytes are already near-compulsory (591 fetch / 370 write MB);
// this targets gather latency hiding, not traffic.

constexpr int BGRAPH = 8;
constexpr int HID    = 768;
constexpr int MAXLEN = 15360;
constexpr int TB     = 16;    // tokens per block
constexpr int BLOCK  = 192;   // 192 threads * float4 = 768 cols

typedef float nfloat4 __attribute__((ext_vector_type(4)));

__device__ __forceinline__ void st_nt4(float4* p, float4 v) {
    nfloat4 nv;
    nv.x = v.x; nv.y = v.y; nv.z = v.z; nv.w = v.w;
    __builtin_nontemporal_store(nv, (nfloat4*)p);
}
__device__ __forceinline__ void st_nt1(float* p, float v) {
    __builtin_nontemporal_store(v, p);
}

__global__ __launch_bounds__(BLOCK)
void gft_kernel(const float* __restrict__ embedW,   // [50257,768]
                const float* __restrict__ lapW,     // [64,768]
                const float* __restrict__ orderW,   // [2,768]
                const float* __restrict__ eig,      // [N,32]
                const int*   __restrict__ node_data,// [N,4]
                const int*   __restrict__ edge_data,// [E,4]
                const int*   __restrict__ edge_index,// [2,E]
                const int*   __restrict__ node_num, // [8]
                const int*   __restrict__ edge_num, // [8]
                int E,
                float* __restrict__ outF,
                float* __restrict__ outM,
                float* __restrict__ outI)
{
    const int b   = blockIdx.y;
    const int t0  = blockIdx.x * TB;
    const int tid = threadIdx.x;

    // prefix sums over the 8 graphs (uniform scalar loads)
    int ns = 0, es = 0, nn = 0, en = 0;
    #pragma unroll
    for (int g = 0; g < BGRAPH; ++g) {
        int nv = node_num[g], ev = edge_num[g];
        if (g < b)  { ns += nv; es += ev; }
        if (g == b) { nn = nv;  en = ev; }
    }
    const int seq = nn + en;

    float* rowF = outF + ((size_t)b * MAXLEN + t0) * HID;
    const float4 z4 = make_float4(0.f, 0.f, 0.f, 0.f);

    if (t0 >= seq) {
        // whole tile is padding: zero feature, mask=1, index=0
        #pragma unroll
        for (int tok = 0; tok < TB; ++tok) {
            st_nt4((float4*)(rowF + (size_t)tok * HID) + tid, z4);
        }
        if (tid < TB) {
            int t = t0 + tid;
            st_nt1(&outM[b * MAXLEN + t], 1.0f);
            st_nt1(&outI[((size_t)b * MAXLEN + t) * 2 + 0], 0.f);
            st_nt1(&outI[((size_t)b * MAXLEN + t) * 2 + 1], 0.f);
        }
        return;
    }

    __shared__ float sh_eig[64][TB];   // [j][tok]
    __shared__ int   sh_ids[TB][4];
    __shared__ int   sh_i0[TB], sh_i1[TB], sh_gA[TB], sh_gB[TB];

    // ---- phase 0: token metadata (one thread per token) ----
    if (tid < TB) {
        int t = t0 + tid;
        int i0 = 0, i1 = 0, gA = -1, gB = -1;
        int id0 = 0, id1 = 0, id2 = 0, id3 = 0;
        if (t < seq) {
            if (t < nn) {               // node token
                int g = ns + t;
                i0 = t; i1 = t; gA = g; gB = g;
                id0 = node_data[g * 4 + 0];
                id1 = node_data[g * 4 + 1];
                id2 = node_data[g * 4 + 2];
                id3 = node_data[g * 4 + 3];
            } else {                    // edge token
                int ge = es + (t - nn);
                i0 = edge_index[ge];
                i1 = edge_index[E + ge];
                gA = ns + i0; gB = ns + i1;
                id0 = edge_data[ge * 4 + 0];
                id1 = edge_data[ge * 4 + 1];
                id2 = edge_data[ge * 4 + 2];
                id3 = edge_data[ge * 4 + 3];
            }
        }
        sh_i0[tid] = i0; sh_i1[tid] = i1;
        sh_gA[tid] = gA; sh_gB[tid] = gB;
        sh_ids[tid][0] = id0; sh_ids[tid][1] = id1;
        sh_ids[tid][2] = id2; sh_ids[tid][3] = id3;
    }
    __syncthreads();

    // ---- phase 1: stage eig pairs into LDS [j][tok] (first 128 threads, 8 j's each) ----
    if (tid < 128) {
        int tok   = tid >> 3;           // 0..15
        int jbase = (tid & 7) * 8;      // 0..56
        int gA = sh_gA[tok], gB = sh_gB[tok];
        #pragma unroll
        for (int jj = 0; jj < 8; ++jj) {
            int j = jbase + jj;
            float v = 0.f;
            if (j < 32) { if (gA >= 0) v = eig[(size_t)gA * 32 + j]; }
            else        { if (gB >= 0) v = eig[(size_t)gB * 32 + (j - 32)]; }
            sh_eig[j][tok] = v;
        }
    }
    __syncthreads();

    // ---- phase 2: lap projection. acc[tok] = float4 over this thread's col group ----
    // (byte-identical to the 296us R2 version -- do not disturb)
    float4 acc[TB];
    #pragma unroll
    for (int i = 0; i < TB; ++i) acc[i] = z4;

    for (int j = 0; j < 64; ++j) {
        float4 w = ((const float4*)(lapW + j * HID))[tid];
        const float4* ev = (const float4*)(&sh_eig[j][0]);
        #pragma unroll
        for (int q = 0; q < TB / 4; ++q) {
            float4 e4 = ev[q];
            acc[q*4+0].x += e4.x * w.x; acc[q*4+0].y += e4.x * w.y;
            acc[q*4+0].z += e4.x * w.z; acc[q*4+0].w += e4.x * w.w;
            acc[q*4+1].x += e4.y * w.x; acc[q*4+1].y += e4.y * w.y;
            acc[q*4+1].z += e4.y * w.z; acc[q*4+1].w += e4.y * w.w;
            acc[q*4+2].x += e4.z * w.x; acc[q*4+2].y += e4.z * w.y;
            acc[q*4+2].z += e4.z * w.z; acc[q*4+2].w += e4.z * w.w;
            acc[q*4+3].x += e4.w * w.x; acc[q*4+3].y += e4.w * w.y;
            acc[q*4+3].z += e4.w * w.z; acc[q*4+3].w += e4.w * w.w;
        }
    }

    // ---- phase 3: embedding gather-sum, batched 4 tokens (16 loads in flight) ----
    #pragma unroll
    for (int base = 0; base < TB; base += 4) {
        float4 eb[4][4];   // static-indexed in fully unrolled loops -> registers
        #pragma unroll
        for (int tk = 0; tk < 4; ++tk) {
            #pragma unroll
            for (int r = 0; r < 4; ++r) {
                eb[tk][r] = ((const float4*)(embedW + (size_t)sh_ids[base + tk][r] * HID))[tid];
            }
        }
        #pragma unroll
        for (int tk = 0; tk < 4; ++tk) {
            const int tok = base + tk;
            const int t = t0 + tok;
            float4* dst = (float4*)(rowF + (size_t)tok * HID) + tid;
            float4 s = acc[tok];
            #pragma unroll
            for (int r = 0; r < 4; ++r) {
                s.x += eb[tk][r].x; s.y += eb[tk][r].y;
                s.z += eb[tk][r].z; s.w += eb[tk][r].w;
            }
            int ord = (sh_i0[tok] == sh_i1[tok]) ? 1 : 0;
            float4 o = ((const float4*)(orderW + (size_t)ord * HID))[tid];
            s.x += o.x; s.y += o.y; s.z += o.z; s.w += o.w;
            if (t >= seq) s = z4;
            st_nt4(dst, s);
        }
    }

    if (tid < TB) {
        int t = t0 + tid;
        bool pad = (t >= seq);
        st_nt1(&outM[b * MAXLEN + t], pad ? 1.0f : 0.0f);
        st_nt1(&outI[((size_t)b * MAXLEN + t) * 2 + 0], pad ? 0.f : (float)sh_i0[tid]);
        st_nt1(&outI[((size_t)b * MAXLEN + t) * 2 + 1], pad ? 0.f : (float)sh_i1[tid]);
    }
}

extern "C" void kernel_launch(void* const* d_in, const int* in_sizes, int n_in,
                              void* d_out, int out_size, void* d_ws, size_t ws_size,
                              hipStream_t stream) {
    const float* embedW     = (const float*)d_in[0];
    const float* lapW       = (const float*)d_in[1];
    const float* orderW     = (const float*)d_in[2];
    const float* eig        = (const float*)d_in[3];
    const int*   node_data  = (const int*)d_in[4];
    const int*   edge_data  = (const int*)d_in[5];
    const int*   edge_index = (const int*)d_in[6];
    const int*   node_num   = (const int*)d_in[7];
    const int*   edge_num   = (const int*)d_in[8];
    const int E = in_sizes[6] / 2;

    float* outF = (float*)d_out;
    float* outM = outF + (size_t)BGRAPH * MAXLEN * HID;
    float* outI = outM + (size_t)BGRAPH * MAXLEN;

    dim3 grid(MAXLEN / TB, BGRAPH);
    gft_kernel<<<grid, BLOCK, 0, stream>>>(embedW, lapW, orderW, eig,
                                           node_data, edge_data, edge_index,
                                           node_num, edge_num, E,
                                           outF, outM, outI);
}